// Round 14
// baseline (259.666 us; speedup 1.0000x reference)
//
#include <hip/hip_runtime.h>

// HierarchicalGraphSAGE bf16-MFMA version, R30 (2nd resubmit — R12 and R13
// benches were both GPUAcquisitionTimeouts; kernel has never run).
// N=50000, E=800000, D=128, OUT=64, G=64.
//
//  R30 = R29 (232.8us best) minus the redundant bf16 self-term copies:
//   - x_bf / hA DELETED. The GEMM self-term (s>=4) now reads the block's
//     OWN fp8 rows (h8_in, L2-hot from the gather) and cvts fp8->bf16
//     in-register: lane l needs exactly uint2 at row(node0+(l&15)),
//     col (s-4)*32+(l>>4)*8 -- contiguous, conversion exact in bf16.
//     Saves per layer ~12.8MB write + ~12.8MB fetch; scatcast -13MB.
//   - Numerics: self term fp8-quantized (agg term already is); R18 error
//     budget: threshold 17.2, absmax was 4.0 -> predicted ~4-6.
//   - Pad-node rows may read garbage/NaN fp8: contaminates only that
//     node's MFMA output row, masked by (node<n) in the epilogue.
//   - Everything else (scatter/fillfine/hist/gsum/finalred) R29 verbatim.

typedef __bf16 bf16x8 __attribute__((ext_vector_type(8)));
typedef float f32x4 __attribute__((ext_vector_type(4)));
typedef float f32x2 __attribute__((ext_vector_type(2)));

#define NBMAX 512
#define CH 4096
#define NSB 160
#define SSTRIDE 3072

static __device__ __forceinline__ unsigned short f2bf(float f) {
    unsigned u = __builtin_bit_cast(unsigned, f);
    return (unsigned short)((u + 0x7fffu + ((u >> 16) & 1u)) >> 16);
}
static __device__ __forceinline__ uint2 pk8_fp8(const float* f) {
    int lo = 0, hi = 0;
    lo = __builtin_amdgcn_cvt_pk_fp8_f32(f[0], f[1], lo, false);
    lo = __builtin_amdgcn_cvt_pk_fp8_f32(f[2], f[3], lo, true);
    hi = __builtin_amdgcn_cvt_pk_fp8_f32(f[4], f[5], hi, false);
    hi = __builtin_amdgcn_cvt_pk_fp8_f32(f[6], f[7], hi, true);
    return make_uint2((unsigned)lo, (unsigned)hi);
}
static __device__ __forceinline__ unsigned char f2fp8(float v) {
    return (unsigned char)(__builtin_amdgcn_cvt_pk_fp8_f32(v, v, 0, false) & 0xff);
}

// ------------- scatter (fixed-stride, fence-free) + cast + weight pack -----
// blocks [0, NSB)          : bucket scatter into binned[b*SSTRIDE + r]
// blocks [NSB, +nxblk)     : x -> fp8 rows (bf16 frag copy DELETED)
// blocks [NSB+nxblk, +256) : weight frag pack (2 layers)
__global__ __launch_bounds__(256) void k_scatcast(
    const int* __restrict__ ei, unsigned* __restrict__ binned,
    unsigned* __restrict__ gbcnt, int E, int nb, int epb,
    const float* __restrict__ x,
    unsigned char* __restrict__ x8, int n8, int nxblk,
    const float* __restrict__ W1l, const float* __restrict__ W1r,
    const float* __restrict__ W2l, const float* __restrict__ W2r,
    unsigned short* __restrict__ Whi)
{
    __shared__ int lcnt[NBMAX];
    __shared__ int lofs[NBMAX];
    int bid = blockIdx.x;
    int t = threadIdx.x;
    if (bid < NSB) {
        int b0 = bid * epb;
        int b1 = min(b0 + epb, E);
        for (int i = t; i < nb; i += 256) lcnt[i] = 0;
        __syncthreads();
        for (int i = b0 + t; i < b1; i += 256)
            atomicAdd(&lcnt[ei[E + i] >> 7], 1);
        __syncthreads();
        for (int i = t; i < nb; i += 256) {
            int c = lcnt[i];
            lofs[i] = (c > 0) ? (int)atomicAdd(&gbcnt[i], (unsigned)c) : 0;
            lcnt[i] = 0;
        }
        __syncthreads();
        for (int i = b0 + t; i < b1; i += 256) {
            int s = ei[i];
            int d = ei[E + i];
            int b = d >> 7;
            int r = lofs[b] + atomicAdd(&lcnt[b], 1);
            if (r < SSTRIDE)
                binned[(size_t)b * SSTRIDE + r] =
                    (unsigned)s | ((unsigned)(d & 127) << 16);
        }
    } else if (bid < NSB + nxblk) {
        int i = (bid - NSB) * 256 + t;
        if (i >= n8) return;
        float f[8];
        *(float4*)(f + 0) = *(const float4*)(x + (size_t)i * 8);
        *(float4*)(f + 4) = *(const float4*)(x + (size_t)i * 8 + 4);
        *(uint2*)(x8 + (size_t)i * 8) = pk8_fp8(f);
    } else {
        int wb = bid - NSB - nxblk;   // 0..255 (2 layers)
        int layer = wb >> 7;
        int j = wb & 127;
        int k = t;
        const float* Wl = (layer == 0) ? W1l : W2l;
        const float* Wr = (layer == 0) ? W1r : W2r;
        float w = (k < 128) ? Wl[j * 128 + k] : Wr[j * 128 + k - 128];
        int js = j >> 4, mr = j & 15;
        int s = k >> 5, quad = (k >> 3) & 3, e = k & 7;
        size_t o = (size_t)layer * 32768
                 + ((size_t)(js * 8 + s) * 64 + quad * 16 + mr) * 8 + e;
        Whi[o] = f2bf(w);
    }
}

// ------- per-bucket fine sort -> DENSE csr + starts + gestart --------------
__global__ __launch_bounds__(256) void k_fillfine(
    const unsigned* __restrict__ binned, const unsigned* __restrict__ gbcnt,
    const int* __restrict__ batch, int* __restrict__ starts,
    unsigned short* __restrict__ csr_src, int* __restrict__ gestart,
    int E, int nb, int n)
{
    __shared__ int lc[128];
    __shared__ int lpos[128];
    __shared__ int red[256];
    int b = blockIdx.x;
    int t = threadIdx.x;
    int node0 = b << 7;
    int bs = b * SSTRIDE;
    int cb = min((int)gbcnt[b], SSTRIDE);
    int be = bs + cb;

    // dense base: exclusive prefix over gbcnt
    int part = 0;
    for (int i = t; i < b; i += 256) part += (int)gbcnt[i];
    red[t] = part;
    __syncthreads();
#pragma unroll
    for (int off = 128; off > 0; off >>= 1) {
        if (t < off) red[t] += red[t + off];
        __syncthreads();
    }
    int wb = red[0];

    if (t < 128) lc[t] = 0;
    __syncthreads();
    for (int i = bs + t; i < be; i += 256)
        atomicAdd(&lc[(binned[i] >> 16) & 127], 1);
    __syncthreads();
    int v = (t < 128) ? lc[t] : 0;
    if (t < 128) lpos[t] = v;
    __syncthreads();
#pragma unroll
    for (int off = 1; off < 128; off <<= 1) {
        int u = (t >= off && t < 128) ? lpos[t - off] : 0;
        __syncthreads();
        if (t < 128) lpos[t] += u;
        __syncthreads();
    }
    int excl = (t < 128) ? (lpos[t] - v) : 0;
    __syncthreads();
    if (t < 128) {
        int node = node0 + t;
        if (node < n) {
            int st = wb + excl;
            starts[node] = st;
            int bc = batch[node];
            int bp = (node == 0) ? -1 : batch[node - 1];
            for (int g = bp + 1; g <= bc; ++g) gestart[g] = st;
            if (node == n - 1)
                for (int g = bc + 1; g <= 64; ++g) gestart[g] = E;
        }
        lpos[t] = wb + excl;
    }
    if (b == nb - 1 && t == 0) starts[n] = E;
    __syncthreads();
    for (int i = bs + t; i < be; i += 256) {
        unsigned e = binned[i];
        int slot = atomicAdd(&lpos[(e >> 16) & 127], 1);
        csr_src[slot] = (unsigned short)(e & 0xffffu);
    }
}

// ---------------- shared gather helpers (f32x2 packed accumulators) --------
#define ACC8P(v)                                                        \
    do {                                                                \
        f32x2 p0 = __builtin_amdgcn_cvt_pk_f32_fp8((v).x, false);       \
        f32x2 p1 = __builtin_amdgcn_cvt_pk_f32_fp8((v).x, true);        \
        f32x2 p2 = __builtin_amdgcn_cvt_pk_f32_fp8((v).y, false);       \
        f32x2 p3 = __builtin_amdgcn_cvt_pk_f32_fp8((v).y, true);        \
        A01 += p0; A23 += p1; A45 += p2; A67 += p3;                     \
    } while (0)

#define PROC_CHUNK(idxv, cntv)                                          \
    {                                                                   \
        int j = 0;                                                      \
        for (; j + 16 <= (cntv); j += 16) {                             \
            int s0 = __shfl((int)(idxv), j + eg);                       \
            int s1 = __shfl((int)(idxv), j + 4 + eg);                   \
            int s2 = __shfl((int)(idxv), j + 8 + eg);                   \
            int s3 = __shfl((int)(idxv), j + 12 + eg);                  \
            uint2 v0 = *(const uint2*)(hrow + (size_t)s0 * 128);        \
            uint2 v1 = *(const uint2*)(hrow + (size_t)s1 * 128);        \
            uint2 v2 = *(const uint2*)(hrow + (size_t)s2 * 128);        \
            uint2 v3 = *(const uint2*)(hrow + (size_t)s3 * 128);        \
            ACC8P(v0);                                                  \
            ACC8P(v1);                                                  \
            ACC8P(v2);                                                  \
            ACC8P(v3);                                                  \
        }                                                               \
        for (; j + 4 <= (cntv); j += 4) {                               \
            int s0 = __shfl((int)(idxv), j + eg);                       \
            uint2 v0 = *(const uint2*)(hrow + (size_t)s0 * 128);        \
            ACC8P(v0);                                                  \
        }                                                               \
        if (j < (cntv)) {                                               \
            int k = j + eg;                                             \
            int sm = __shfl((int)(idxv), (k < (cntv)) ? k : ((cntv) - 1)); \
            uint2 v = *(const uint2*)(hrow + (size_t)sm * 128);         \
            if (k >= (cntv)) v = make_uint2(0u, 0u);                    \
            ACC8P(v);                                                   \
        }                                                               \
    }

#define REDUCE8P()                                                      \
    A01.x += __shfl_xor(A01.x, 16); A01.x += __shfl_xor(A01.x, 32);     \
    A01.y += __shfl_xor(A01.y, 16); A01.y += __shfl_xor(A01.y, 32);     \
    A23.x += __shfl_xor(A23.x, 16); A23.x += __shfl_xor(A23.x, 32);     \
    A23.y += __shfl_xor(A23.y, 16); A23.y += __shfl_xor(A23.y, 32);     \
    A45.x += __shfl_xor(A45.x, 16); A45.x += __shfl_xor(A45.x, 32);     \
    A45.y += __shfl_xor(A45.y, 16); A45.y += __shfl_xor(A45.y, 32);     \
    A67.x += __shfl_xor(A67.x, 16); A67.x += __shfl_xor(A67.x, 32);     \
    A67.y += __shfl_xor(A67.y, 16); A67.y += __shfl_xor(A67.y, 32);

// ------- fused SAGE layer, 512 thr / 8 waves / 16 nodes (+ hist fold) ------
// blocks [0, laygrid): layer (2 nodes/wave gather; 1 j-tile/wave GEMM;
//   self-term s>=4 read from own fp8 rows, cvt in-register).
// blocks [laygrid, ...): histogram/indicator (layer-1 launch only).
__global__ __launch_bounds__(512) void k_layer(
    const unsigned char* __restrict__ h8_in, const int* __restrict__ starts,
    const unsigned short* __restrict__ csr,
    const unsigned short* __restrict__ Whi, const float* __restrict__ bl,
    unsigned char* __restrict__ out8, unsigned short* __restrict__ h2tb,
    const int* __restrict__ gestart, const int* __restrict__ batch,
    unsigned short* __restrict__ cntb,
    int n, int nsp, int mode, int laygrid, int nch)
{
    __shared__ unsigned smem[CH];                          // 16KB union
    unsigned short* sagg = (unsigned short*)smem;          // 4KB (layer)
    unsigned char*  s8   = (unsigned char*)(smem + 1024);  // 2KB (layer, mode 0)
    int t = threadIdx.x;

    if ((int)blockIdx.x >= laygrid) {
        // ---- histogram / pool-indicator branch (512 threads) ----
        unsigned* lc = smem;
        int hb = blockIdx.x - laygrid;
        int c = hb % nch;
        int gr = hb / nch;
        int s0 = c * CH;
        if (gr < 64) {
            for (int i = t; i < CH; i += 512) lc[i] = 0;
            __syncthreads();
            int e0 = gestart[gr], e1 = gestart[gr + 1];
            for (int i = e0 + t; i < e1; i += 512) {
                unsigned d = (unsigned)((int)csr[i] - s0);
                if (d < (unsigned)CH) atomicAdd(&lc[d], 1u);
            }
            __syncthreads();
            for (int i = t; i < CH; i += 512) {
                int s = s0 + i;
                if (s < nsp)
                    cntb[(size_t)gr * nsp + s] = f2bf((float)lc[i]);
            }
        } else {
            int g2 = gr - 64;
            for (int i = t; i < CH; i += 512) {
                int s = s0 + i;
                if (s < nsp)
                    cntb[(size_t)gr * nsp + s] =
                        (s < n && batch[s] == g2) ? (unsigned short)0x3f80
                                                  : (unsigned short)0;
            }
        }
        return;
    }

    int wv = t >> 6;        // 0..7
    int lane = t & 63;
    int node0 = blockIdx.x * 16;

    // ---- gather phase: 2 nodes per wave ----
    {
        int eg = lane >> 4;
        int fb = lane & 15;
        const unsigned char* hrow = h8_in + fb * 8;
        int nodeA = node0 + wv * 2;
        int st[3];
#pragma unroll
        for (int r = 0; r < 3; ++r) {
            int nn = nodeA + r;
            st[r] = starts[nn > n ? n : nn];
        }
        unsigned idx2[2];
#pragma unroll
        for (int r = 0; r < 2; ++r)
            idx2[r] = (st[r] + lane < st[r + 1]) ? (unsigned)csr[st[r] + lane] : 0u;

#pragma unroll
        for (int r = 0; r < 2; ++r) {
            f32x2 A01 = (f32x2){0.f, 0.f}, A23 = (f32x2){0.f, 0.f},
                  A45 = (f32x2){0.f, 0.f}, A67 = (f32x2){0.f, 0.f};
            int deg = st[r + 1] - st[r];
            int c0 = min(64, deg);
            PROC_CHUNK(idx2[r], c0)
            for (int base = st[r] + 64; base < st[r + 1]; base += 64) {
                int cnt2 = min(64, st[r + 1] - base);
                unsigned idx = (base + lane < st[r + 1]) ? (unsigned)csr[base + lane] : 0u;
                PROC_CHUNK(idx, cnt2)
            }
            REDUCE8P()
            if (eg == 0) {
                int ln = wv * 2 + r;   // 0..15
                unsigned u0 = (unsigned)f2bf(A01.x) | ((unsigned)f2bf(A01.y) << 16);
                unsigned u1 = (unsigned)f2bf(A23.x) | ((unsigned)f2bf(A23.y) << 16);
                unsigned u2 = (unsigned)f2bf(A45.x) | ((unsigned)f2bf(A45.y) << 16);
                unsigned u3 = (unsigned)f2bf(A67.x) | ((unsigned)f2bf(A67.y) << 16);
                size_t dst = (size_t)(fb >> 2) * 512 + (size_t)((fb & 3) * 16 + ln) * 8;
                *(uint4*)(sagg + dst) = make_uint4(u0, u1, u2, u3);
            }
        }
    }
    __syncthreads();

    // ---- GEMM phase: wave wv owns j-tile js = wv (16 cols) ----
    int quad = lane >> 4;
    int mr = lane & 15;
    int js = wv;

    f32x4 acc = (f32x4){0.f, 0.f, 0.f, 0.f};

    const unsigned short* wp = Whi + (size_t)js * 4096 + (size_t)lane * 8;
    const unsigned short* sa = sagg + (size_t)lane * 8;
    // self-term fp8 row: lane holds node node0+mr, cols (s-4)*32 + quad*8 + e
    const unsigned char* srow = h8_in + (size_t)(node0 + mr) * 128 + quad * 8;

    uint4 pw[2];
    uint4 pa[2];
    uint2 p8[2];
#define LAYER_LOAD(s, b)                                                  \
    do {                                                                  \
        pw[b] = *(const uint4*)(wp + (size_t)(s) * 512);                  \
        if ((s) < 4)                                                      \
            pa[b] = *(const uint4*)(sa + (size_t)(s) * 512);              \
        else                                                              \
            p8[b] = *(const uint2*)(srow + ((s) - 4) * 32);                \
    } while (0)

    LAYER_LOAD(0, 0);
    LAYER_LOAD(1, 1);
#pragma unroll
    for (int s = 0; s < 8; ++s) {
        int b = s & 1;
        bf16x8 bh = __builtin_bit_cast(bf16x8, pw[b]);
        bf16x8 A0;
        if (s < 4) {
            A0 = __builtin_bit_cast(bf16x8, pa[b]);
        } else {
            f32x2 q0 = __builtin_amdgcn_cvt_pk_f32_fp8(p8[b].x, false);
            f32x2 q1 = __builtin_amdgcn_cvt_pk_f32_fp8(p8[b].x, true);
            f32x2 q2 = __builtin_amdgcn_cvt_pk_f32_fp8(p8[b].y, false);
            f32x2 q3 = __builtin_amdgcn_cvt_pk_f32_fp8(p8[b].y, true);
            unsigned w0 = (unsigned)f2bf(q0.x) | ((unsigned)f2bf(q0.y) << 16);
            unsigned w1 = (unsigned)f2bf(q1.x) | ((unsigned)f2bf(q1.y) << 16);
            unsigned w2 = (unsigned)f2bf(q2.x) | ((unsigned)f2bf(q2.y) << 16);
            unsigned w3 = (unsigned)f2bf(q3.x) | ((unsigned)f2bf(q3.y) << 16);
            uint4 au = make_uint4(w0, w1, w2, w3);
            A0 = __builtin_bit_cast(bf16x8, au);
        }
        acc = __builtin_amdgcn_mfma_f32_16x16x32_bf16(A0, bh, acc, 0, 0, 0);
        if (s + 2 < 8) LAYER_LOAD(s + 2, b);
    }
#undef LAYER_LOAD

    // ---- epilogue: bias/relu, LDS-stage, coalesced dump ----
    int col = js * 16 + mr;
    float bias = bl[col];
    float vv[4];
#pragma unroll
    for (int r = 0; r < 4; ++r) {
        int node = node0 + quad * 4 + r;
        float v = fmaxf(acc[r] + bias, 0.f);
        vv[r] = (node < n) ? v : 0.f;
    }
    __syncthreads();   // all waves done reading sagg frags
    if (mode == 0) {
#pragma unroll
        for (int r = 0; r < 4; ++r)
            s8[(quad * 4 + r) * 128 + col] = f2fp8(vv[r]);
        __syncthreads();
        int nl = t >> 5;
        if (node0 + nl < n)
            *(unsigned*)(out8 + (size_t)(node0 + nl) * 128 + (t & 31) * 4) =
                *(const unsigned*)(s8 + nl * 128 + (t & 31) * 4);
    } else {
        // tiled h2T: tile layout [node/16][col][16]
#pragma unroll
        for (int r = 0; r < 4; ++r)
            sagg[col * 16 + quad * 4 + r] = f2bf(vv[r]);
        __syncthreads();
        *(uint2*)(h2tb + (size_t)blockIdx.x * 2048 + (size_t)t * 4) =
            *(const uint2*)(sagg + (size_t)t * 4);
    }
}

// ------- gsum GEMM: [128 x nsp] cntb x h2tb(tiled)^T -> per-block partials -
__global__ __launch_bounds__(256) void k_gsum(
    const unsigned short* __restrict__ cntb, const unsigned short* __restrict__ h2tb,
    float* __restrict__ part, int nsp, int ksteps, int gb)
{
    int t = threadIdx.x;
    int wv = t >> 6, lane = t & 63;
    int fast = lane & 15;
    int kc = (lane >> 4) * 8;
    int kpb = (ksteps + gb - 1) / gb;
    int k0 = blockIdx.x * kpb, k1 = min(k0 + kpb, ksteps);

    f32x4 accE[8], accP[8];
#pragma unroll
    for (int i = 0; i < 8; ++i) {
        accE[i] = (f32x4){0.f, 0.f, 0.f, 0.f};
        accP[i] = (f32x4){0.f, 0.f, 0.f, 0.f};
    }

    const unsigned short* apE = cntb + (size_t)(wv * 16 + fast) * nsp + kc;
    const unsigned short* apP = apE + (size_t)64 * nsp;

    if (k0 < k1) {
        int kk = k0 * 32 + kc;
        const unsigned short* bt = h2tb + ((size_t)(kk >> 4)) * 2048 + (kk & 15);
        uint4 ca0 = *(const uint4*)(apE + k0 * 32);
        uint4 ca1 = *(const uint4*)(apP + k0 * 32);
        uint4 cb[8];
#pragma unroll
        for (int ft = 0; ft < 8; ++ft)
            cb[ft] = *(const uint4*)(bt + (size_t)(fast + ft * 16) * 16);
        for (int ks = k0; ks < k1; ++ks) {
            int ksn = min(ks + 1, k1 - 1);
            int kkn = ksn * 32 + kc;
            const unsigned short* btn = h2tb + ((size_t)(kkn >> 4)) * 2048 + (kkn & 15);
            uint4 na0 = *(const uint4*)(apE + ksn * 32);
            uint4 na1 = *(const uint4*)(apP + ksn * 32);
            uint4 nb[8];
#pragma unroll
            for (int ft = 0; ft < 8; ++ft)
                nb[ft] = *(const uint4*)(btn + (size_t)(fast + ft * 16) * 16);
            bf16x8 aE = __builtin_bit_cast(bf16x8, ca0);
            bf16x8 aP = __builtin_bit_cast(bf16x8, ca1);
#pragma unroll
            for (int ft = 0; ft < 8; ++ft) {
                bf16x8 bf = __builtin_bit_cast(bf16x8, cb[ft]);
                accE[ft] = __builtin_amdgcn_mfma_f32_16x16x32_bf16(aE, bf, accE[ft], 0, 0, 0);
                accP[ft] = __builtin_amdgcn_mfma_f32_16x16x32_bf16(aP, bf, accP[ft], 0, 0, 0);
            }
            ca0 = na0; ca1 = na1;
#pragma unroll
            for (int ft = 0; ft < 8; ++ft) cb[ft] = nb[ft];
        }
    }
    float* po = part + (size_t)blockIdx.x * 16384;
    int quad = lane >> 4, mr = lane & 15;
#pragma unroll
    for (int ft = 0; ft < 8; ++ft) {
        int col = ft * 16 + mr;
#pragma unroll
        for (int r = 0; r < 4; ++r) {
            po[(size_t)(wv * 16 + quad * 4 + r) * 128 + col] = accE[ft][r];
            po[(size_t)(64 + wv * 16 + quad * 4 + r) * 128 + col] = accP[ft][r];
        }
    }
}

// ------- final: partial reduce (8 unrolled chains) + layer 3 + head --------
__global__ __launch_bounds__(128) void k_finalred(
    const float* __restrict__ part, const int* __restrict__ batch,
    const float* __restrict__ W3l, const float* __restrict__ b3,
    const float* __restrict__ W3r,
    const float* __restrict__ Wlin, const float* __restrict__ blin,
    float* __restrict__ out, int n, int gb)
{
    __shared__ float sE[128], sP[128], tmp[128];
    int g = blockIdx.x;   // 64
    int t = threadIdx.x;  // 128
    float e0 = 0.f, e1 = 0.f, e2 = 0.f, e3 = 0.f;
    float p0 = 0.f, p1 = 0.f, p2 = 0.f, p3 = 0.f;
    int p = 0;
    for (; p + 4 <= gb; p += 4) {
        const float* q0 = part + (size_t)p * 16384;
        const float* q1 = part + (size_t)(p + 1) * 16384;
        const float* q2 = part + (size_t)(p + 2) * 16384;
        const float* q3 = part + (size_t)(p + 3) * 16384;
        e0 += q0[g * 128 + t];        e1 += q1[g * 128 + t];
        e2 += q2[g * 128 + t];        e3 += q3[g * 128 + t];
        p0 += q0[(64 + g) * 128 + t]; p1 += q1[(64 + g) * 128 + t];
        p2 += q2[(64 + g) * 128 + t]; p3 += q3[(64 + g) * 128 + t];
    }
    for (; p < gb; ++p) {
        e0 += part[(size_t)p * 16384 + g * 128 + t];
        p0 += part[(size_t)p * 16384 + (64 + g) * 128 + t];
    }
    sE[t] = (e0 + e1) + (e2 + e3);
    sP[t] = (p0 + p1) + (p2 + p3);

    int lo = 0, hi = n;
    while (lo < hi) { int m = (lo + hi) >> 1; if (batch[m] < g) lo = m + 1; else hi = m; }
    int lb = lo;
    hi = n;
    while (lo < hi) { int m = (lo + hi) >> 1; if (batch[m] < g + 1) lo = m + 1; else hi = m; }
    int cnt = lo - lb;
    float inv = (cnt > 0) ? 1.f / (float)cnt : 0.f;
    __syncthreads();

    float acc = 0.f;
    for (int k = 0; k < 128; ++k)
        acc += sE[k] * W3l[t * 128 + k] + sP[k] * W3r[t * 128 + k];
    tmp[t] = acc * inv + ((cnt > 0) ? b3[t] : 0.f);
    __syncthreads();

    if (t < 64) {
        float o = 0.f;
        for (int k = 0; k < 128; ++k)
            o += tmp[k] * Wlin[t * 128 + k];
        out[g * 64 + t] = o + blin[t];
    }
}

extern "C" void kernel_launch(void* const* d_in, const int* in_sizes, int n_in,
                              void* d_out, int out_size, void* d_ws, size_t ws_size,
                              hipStream_t stream) {
    const float* x     = (const float*)d_in[0];
    const int*   ei    = (const int*)d_in[1];
    const int*   batch = (const int*)d_in[2];
    const float* W1l = (const float*)d_in[3];
    const float* b1l = (const float*)d_in[4];
    const float* W1r = (const float*)d_in[5];
    const float* W2l = (const float*)d_in[6];
    const float* b2l = (const float*)d_in[7];
    const float* W2r = (const float*)d_in[8];
    const float* W3l = (const float*)d_in[9];
    const float* b3l = (const float*)d_in[10];
    const float* W3r = (const float*)d_in[11];
    const float* Wlin = (const float*)d_in[12];
    const float* blin = (const float*)d_in[13];

    const int N = in_sizes[2];       // 50000
    const int E = in_sizes[1] / 2;   // 800000
    const int nb = (N + 127) >> 7;   // 391 buckets
    const int epb = (E + NSB - 1) / NSB;         // 5000
    const int NSP = ((N + 31) / 32) * 32;        // 50016 (mult of 32)
    const int KSTEPS = NSP / 32;                 // 1563
    const int NCH = (NSP + CH - 1) / CH;         // 13
    const int GB = 64;                           // gsum K-split blocks

    size_t off = 0;
    auto alloc = [&](size_t bytes) {
        void* p = (char*)d_ws + off;
        off += (bytes + 255) & ~(size_t)255;
        return p;
    };
    unsigned* gbcnt = (unsigned*)alloc((size_t)NBMAX * 4);
    int* starts     = (int*)alloc((size_t)(N + 128) * 4);
    int* gestart    = (int*)alloc(256 + 64);
    unsigned short* csr_src = (unsigned short*)alloc((size_t)E * 2);
    unsigned*       binned  = (unsigned*)alloc((size_t)nb * SSTRIDE * 4);
    unsigned char*  x8   = (unsigned char*)alloc((size_t)N * 128 + 4096);
    unsigned char*  h1_8 = (unsigned char*)alloc((size_t)N * 128 + 4096);
    unsigned short* h2Tb = (unsigned short*)alloc((size_t)128 * NSP * 2);
    unsigned short* cntb = (unsigned short*)alloc((size_t)128 * NSP * 2);
    unsigned short* Whi  = (unsigned short*)alloc(2 * 128 * 256 * 2);
    float*          part = (float*)alloc((size_t)GB * 16384 * 4);
    (void)ws_size;

    hipMemsetAsync(gbcnt, 0, (size_t)NBMAX * 4, stream);

    int n8 = N * 128 / 8;
    int nxblk = (n8 + 255) / 256;    // 3125

    // 1: scatter + fp8 cast + weight pack (fence-free, fixed-stride)
    k_scatcast<<<NSB + nxblk + 256, 256, 0, stream>>>(
        ei, binned, gbcnt, E, nb, epb,
        x, x8, n8, nxblk, W1l, W1r, W2l, W2r, Whi);
    // 2: per-bucket fine sort -> DENSE csr + starts + gestart
    k_fillfine<<<nb, 256, 0, stream>>>(binned, gbcnt, batch, starts,
                                       csr_src, gestart, E, nb, N);

    int lay_grid  = (N + 15) / 16;    // 3125
    int lay2_grid = NSP / 16;         // 3126 (pad block zero-fills h2Tb tail)
    int hist_grid = 128 * NCH;        // 1664

    // 3: layer 1 (+ hist/indicator fold): gather(x8) + GEMM -> h1 fp8 rows
    k_layer<<<lay_grid + hist_grid, 512, 0, stream>>>(
        x8, starts, csr_src, Whi, b1l, h1_8, h2Tb,
        gestart, batch, cntb, N, NSP, 0, lay_grid, NCH);
    // 4: layer 2: gather(h1_8) + GEMM -> tiled bf16 h2T
    k_layer<<<lay2_grid, 512, 0, stream>>>(
        h1_8, starts, csr_src, Whi + 32768, b2l, h1_8, h2Tb,
        gestart, batch, cntb, N, NSP, 1, lay2_grid, 1);
    // 5: gsumE+gsumP as one 128x128xNSP MFMA GEMM -> per-block partials
    k_gsum<<<GB, 256, 0, stream>>>(cntb, h2Tb, part, NSP, KSTEPS, GB);
    // 6: reduce partials + collapsed layer 3 + head
    k_finalred<<<64, 128, 0, stream>>>(part, batch, W3l, b3l, W3r,
                                       Wlin, blin, (float*)d_out, N, GB);
}

// Round 15
// 231.598 us; speedup vs baseline: 1.1212x; 1.1212x over previous
//
#include <hip/hip_runtime.h>

// HierarchicalGraphSAGE bf16-MFMA version, R31 = exact revert to R29
// (232.8us, session best). R30 (fp8 self-term, -23MB traffic) REGRESSED to
// 259.7us: fetch dropped as predicted but k_layer rose 45.5->60.8us --
// fifth refutation that k_layer is traffic/occupancy/ILP-bound. Its 45us
// is the dependent-chain cost of the random gather; R29 is the optimum.
// N=50000, E=800000, D=128, OUT=64, G=64.
//
//  R29 summary (7 launches):
//   - k_scatcast: fence-free fixed-stride scatter + x->bf16 frags+fp8 rows
//     + weight frag pack, one launch.
//   - k_fillfine: per-bucket fine sort -> DENSE csr/starts/gestart; dense
//     base computed in-block (<=391 L2 loads + tree reduce).
//   - k_layer x2: 512 thr / 8 waves / 16 nodes; 2 nodes/wave serial gather
//     (fp8 rows -> LDS bf16 frags); 1 j-tile/wave MFMA GEMM (agg from LDS,
//     self-term from bf16 frag stream); LDS-staged coalesced epilogues;
//     hist/pool-indicator table folded into layer-1 grid.
//   - k_gsum: graph-sum+pool as one 128x128xNSP bf16-MFMA GEMM (count +
//     indicator table x tiled h2T) -> per-block partials (GB=64).
//   - k_finalred: partial reduce + collapsed layer 3 + mean + head.

typedef __bf16 bf16x8 __attribute__((ext_vector_type(8)));
typedef float f32x4 __attribute__((ext_vector_type(4)));
typedef float f32x2 __attribute__((ext_vector_type(2)));

#define NBMAX 512
#define CH 4096
#define NSB 160
#define SSTRIDE 3072

static __device__ __forceinline__ unsigned short f2bf(float f) {
    unsigned u = __builtin_bit_cast(unsigned, f);
    return (unsigned short)((u + 0x7fffu + ((u >> 16) & 1u)) >> 16);
}
static __device__ __forceinline__ uint2 pk8_fp8(const float* f) {
    int lo = 0, hi = 0;
    lo = __builtin_amdgcn_cvt_pk_fp8_f32(f[0], f[1], lo, false);
    lo = __builtin_amdgcn_cvt_pk_fp8_f32(f[2], f[3], lo, true);
    hi = __builtin_amdgcn_cvt_pk_fp8_f32(f[4], f[5], hi, false);
    hi = __builtin_amdgcn_cvt_pk_fp8_f32(f[6], f[7], hi, true);
    return make_uint2((unsigned)lo, (unsigned)hi);
}
static __device__ __forceinline__ unsigned char f2fp8(float v) {
    return (unsigned char)(__builtin_amdgcn_cvt_pk_fp8_f32(v, v, 0, false) & 0xff);
}

// ------------- scatter (fixed-stride, fence-free) + cast + weight pack -----
// blocks [0, NSB)          : bucket scatter into binned[b*SSTRIDE + r]
// blocks [NSB, +nxblk)     : x -> bf16 frags + fp8 rows
// blocks [NSB+nxblk, +256) : weight frag pack (2 layers)
__global__ __launch_bounds__(256) void k_scatcast(
    const int* __restrict__ ei, unsigned* __restrict__ binned,
    unsigned* __restrict__ gbcnt, int E, int nb, int epb,
    const float* __restrict__ x, unsigned short* __restrict__ xb,
    unsigned char* __restrict__ x8, int n8, int nxblk,
    const float* __restrict__ W1l, const float* __restrict__ W1r,
    const float* __restrict__ W2l, const float* __restrict__ W2r,
    unsigned short* __restrict__ Whi)
{
    __shared__ int lcnt[NBMAX];
    __shared__ int lofs[NBMAX];
    int bid = blockIdx.x;
    int t = threadIdx.x;
    if (bid < NSB) {
        int b0 = bid * epb;
        int b1 = min(b0 + epb, E);
        for (int i = t; i < nb; i += 256) lcnt[i] = 0;
        __syncthreads();
        for (int i = b0 + t; i < b1; i += 256)
            atomicAdd(&lcnt[ei[E + i] >> 7], 1);
        __syncthreads();
        for (int i = t; i < nb; i += 256) {
            int c = lcnt[i];
            lofs[i] = (c > 0) ? (int)atomicAdd(&gbcnt[i], (unsigned)c) : 0;
            lcnt[i] = 0;
        }
        __syncthreads();
        for (int i = b0 + t; i < b1; i += 256) {
            int s = ei[i];
            int d = ei[E + i];
            int b = d >> 7;
            int r = lofs[b] + atomicAdd(&lcnt[b], 1);
            if (r < SSTRIDE)
                binned[(size_t)b * SSTRIDE + r] =
                    (unsigned)s | ((unsigned)(d & 127) << 16);
        }
    } else if (bid < NSB + nxblk) {
        int i = (bid - NSB) * 256 + t;
        if (i >= n8) return;
        float f[8];
        *(float4*)(f + 0) = *(const float4*)(x + (size_t)i * 8);
        *(float4*)(f + 4) = *(const float4*)(x + (size_t)i * 8 + 4);
        ushort4 oa, ob;
        oa.x = f2bf(f[0]); oa.y = f2bf(f[1]); oa.z = f2bf(f[2]); oa.w = f2bf(f[3]);
        ob.x = f2bf(f[4]); ob.y = f2bf(f[5]); ob.z = f2bf(f[6]); ob.w = f2bf(f[7]);
        int node = i >> 4, c = i & 15;
        size_t dstb = (size_t)(node >> 4) * 2048 + (size_t)(c >> 2) * 512
                    + (size_t)((c & 3) * 16 + (node & 15)) * 8;
        *(ushort4*)(xb + dstb) = oa;
        *(ushort4*)(xb + dstb + 4) = ob;
        *(uint2*)(x8 + (size_t)i * 8) = pk8_fp8(f);
    } else {
        int wb = bid - NSB - nxblk;   // 0..255 (2 layers)
        int layer = wb >> 7;
        int j = wb & 127;
        int k = t;
        const float* Wl = (layer == 0) ? W1l : W2l;
        const float* Wr = (layer == 0) ? W1r : W2r;
        float w = (k < 128) ? Wl[j * 128 + k] : Wr[j * 128 + k - 128];
        int js = j >> 4, mr = j & 15;
        int s = k >> 5, quad = (k >> 3) & 3, e = k & 7;
        size_t o = (size_t)layer * 32768
                 + ((size_t)(js * 8 + s) * 64 + quad * 16 + mr) * 8 + e;
        Whi[o] = f2bf(w);
    }
}

// ------- per-bucket fine sort -> DENSE csr + starts + gestart --------------
// Dense base bbase[b] = sum_{i<b} gbcnt[i] computed in-block (<=391 loads).
__global__ __launch_bounds__(256) void k_fillfine(
    const unsigned* __restrict__ binned, const unsigned* __restrict__ gbcnt,
    const int* __restrict__ batch, int* __restrict__ starts,
    unsigned short* __restrict__ csr_src, int* __restrict__ gestart,
    int E, int nb, int n)
{
    __shared__ int lc[128];
    __shared__ int lpos[128];
    __shared__ int red[256];
    int b = blockIdx.x;
    int t = threadIdx.x;
    int node0 = b << 7;
    int bs = b * SSTRIDE;
    int cb = min((int)gbcnt[b], SSTRIDE);
    int be = bs + cb;

    // dense base: exclusive prefix over gbcnt
    int part = 0;
    for (int i = t; i < b; i += 256) part += (int)gbcnt[i];
    red[t] = part;
    __syncthreads();
#pragma unroll
    for (int off = 128; off > 0; off >>= 1) {
        if (t < off) red[t] += red[t + off];
        __syncthreads();
    }
    int wb = red[0];

    if (t < 128) lc[t] = 0;
    __syncthreads();
    for (int i = bs + t; i < be; i += 256)
        atomicAdd(&lc[(binned[i] >> 16) & 127], 1);
    __syncthreads();
    int v = (t < 128) ? lc[t] : 0;
    if (t < 128) lpos[t] = v;
    __syncthreads();
#pragma unroll
    for (int off = 1; off < 128; off <<= 1) {
        int u = (t >= off && t < 128) ? lpos[t - off] : 0;
        __syncthreads();
        if (t < 128) lpos[t] += u;
        __syncthreads();
    }
    int excl = (t < 128) ? (lpos[t] - v) : 0;
    __syncthreads();
    if (t < 128) {
        int node = node0 + t;
        if (node < n) {
            int st = wb + excl;
            starts[node] = st;
            int bc = batch[node];
            int bp = (node == 0) ? -1 : batch[node - 1];
            for (int g = bp + 1; g <= bc; ++g) gestart[g] = st;
            if (node == n - 1)
                for (int g = bc + 1; g <= 64; ++g) gestart[g] = E;
        }
        lpos[t] = wb + excl;
    }
    if (b == nb - 1 && t == 0) starts[n] = E;
    __syncthreads();
    for (int i = bs + t; i < be; i += 256) {
        unsigned e = binned[i];
        int slot = atomicAdd(&lpos[(e >> 16) & 127], 1);
        csr_src[slot] = (unsigned short)(e & 0xffffu);
    }
}

// ---------------- shared gather helpers (f32x2 packed accumulators) --------
#define ACC8P(v)                                                        \
    do {                                                                \
        f32x2 p0 = __builtin_amdgcn_cvt_pk_f32_fp8((v).x, false);       \
        f32x2 p1 = __builtin_amdgcn_cvt_pk_f32_fp8((v).x, true);        \
        f32x2 p2 = __builtin_amdgcn_cvt_pk_f32_fp8((v).y, false);       \
        f32x2 p3 = __builtin_amdgcn_cvt_pk_f32_fp8((v).y, true);        \
        A01 += p0; A23 += p1; A45 += p2; A67 += p3;                     \
    } while (0)

#define PROC_CHUNK(idxv, cntv)                                          \
    {                                                                   \
        int j = 0;                                                      \
        for (; j + 16 <= (cntv); j += 16) {                             \
            int s0 = __shfl((int)(idxv), j + eg);                       \
            int s1 = __shfl((int)(idxv), j + 4 + eg);                   \
            int s2 = __shfl((int)(idxv), j + 8 + eg);                   \
            int s3 = __shfl((int)(idxv), j + 12 + eg);                  \
            uint2 v0 = *(const uint2*)(hrow + (size_t)s0 * 128);        \
            uint2 v1 = *(const uint2*)(hrow + (size_t)s1 * 128);        \
            uint2 v2 = *(const uint2*)(hrow + (size_t)s2 * 128);        \
            uint2 v3 = *(const uint2*)(hrow + (size_t)s3 * 128);        \
            ACC8P(v0);                                                  \
            ACC8P(v1);                                                  \
            ACC8P(v2);                                                  \
            ACC8P(v3);                                                  \
        }                                                               \
        for (; j + 4 <= (cntv); j += 4) {                               \
            int s0 = __shfl((int)(idxv), j + eg);                       \
            uint2 v0 = *(const uint2*)(hrow + (size_t)s0 * 128);        \
            ACC8P(v0);                                                  \
        }                                                               \
        if (j < (cntv)) {                                               \
            int k = j + eg;                                             \
            int sm = __shfl((int)(idxv), (k < (cntv)) ? k : ((cntv) - 1)); \
            uint2 v = *(const uint2*)(hrow + (size_t)sm * 128);         \
            if (k >= (cntv)) v = make_uint2(0u, 0u);                    \
            ACC8P(v);                                                   \
        }                                                               \
    }

#define REDUCE8P()                                                      \
    A01.x += __shfl_xor(A01.x, 16); A01.x += __shfl_xor(A01.x, 32);     \
    A01.y += __shfl_xor(A01.y, 16); A01.y += __shfl_xor(A01.y, 32);     \
    A23.x += __shfl_xor(A23.x, 16); A23.x += __shfl_xor(A23.x, 32);     \
    A23.y += __shfl_xor(A23.y, 16); A23.y += __shfl_xor(A23.y, 32);     \
    A45.x += __shfl_xor(A45.x, 16); A45.x += __shfl_xor(A45.x, 32);     \
    A45.y += __shfl_xor(A45.y, 16); A45.y += __shfl_xor(A45.y, 32);     \
    A67.x += __shfl_xor(A67.x, 16); A67.x += __shfl_xor(A67.x, 32);     \
    A67.y += __shfl_xor(A67.y, 16); A67.y += __shfl_xor(A67.y, 32);

// ------- fused SAGE layer, 512 thr / 8 waves / 16 nodes (+ hist fold) ------
// blocks [0, laygrid): layer (2 nodes/wave gather; 1 j-tile/wave GEMM).
// blocks [laygrid, ...): histogram/indicator (layer-1 launch only).
__global__ __launch_bounds__(512) void k_layer(
    const unsigned char* __restrict__ h8_in, const int* __restrict__ starts,
    const unsigned short* __restrict__ csr, const unsigned short* __restrict__ hf,
    const unsigned short* __restrict__ Whi, const float* __restrict__ bl,
    unsigned short* __restrict__ outf, unsigned char* __restrict__ out8,
    unsigned short* __restrict__ h2tb,
    const int* __restrict__ gestart, const int* __restrict__ batch,
    unsigned short* __restrict__ cntb,
    int n, int nsp, int mode, int laygrid, int nch)
{
    __shared__ unsigned smem[CH];                          // 16KB union
    unsigned short* sagg = (unsigned short*)smem;          // 4KB (layer)
    unsigned char*  s8   = (unsigned char*)(smem + 1024);  // 2KB (layer, mode 0)
    int t = threadIdx.x;

    if ((int)blockIdx.x >= laygrid) {
        // ---- histogram / pool-indicator branch (512 threads) ----
        unsigned* lc = smem;
        int hb = blockIdx.x - laygrid;
        int c = hb % nch;
        int gr = hb / nch;
        int s0 = c * CH;
        if (gr < 64) {
            for (int i = t; i < CH; i += 512) lc[i] = 0;
            __syncthreads();
            int e0 = gestart[gr], e1 = gestart[gr + 1];
            for (int i = e0 + t; i < e1; i += 512) {
                unsigned d = (unsigned)((int)csr[i] - s0);
                if (d < (unsigned)CH) atomicAdd(&lc[d], 1u);
            }
            __syncthreads();
            for (int i = t; i < CH; i += 512) {
                int s = s0 + i;
                if (s < nsp)
                    cntb[(size_t)gr * nsp + s] = f2bf((float)lc[i]);
            }
        } else {
            int g2 = gr - 64;
            for (int i = t; i < CH; i += 512) {
                int s = s0 + i;
                if (s < nsp)
                    cntb[(size_t)gr * nsp + s] =
                        (s < n && batch[s] == g2) ? (unsigned short)0x3f80
                                                  : (unsigned short)0;
            }
        }
        return;
    }

    int wv = t >> 6;        // 0..7
    int lane = t & 63;
    int node0 = blockIdx.x * 16;

    // ---- gather phase: 2 nodes per wave ----
    {
        int eg = lane >> 4;
        int fb = lane & 15;
        const unsigned char* hrow = h8_in + fb * 8;
        int nodeA = node0 + wv * 2;
        int st[3];
#pragma unroll
        for (int r = 0; r < 3; ++r) {
            int nn = nodeA + r;
            st[r] = starts[nn > n ? n : nn];
        }
        unsigned idx2[2];
#pragma unroll
        for (int r = 0; r < 2; ++r)
            idx2[r] = (st[r] + lane < st[r + 1]) ? (unsigned)csr[st[r] + lane] : 0u;

#pragma unroll
        for (int r = 0; r < 2; ++r) {
            f32x2 A01 = (f32x2){0.f, 0.f}, A23 = (f32x2){0.f, 0.f},
                  A45 = (f32x2){0.f, 0.f}, A67 = (f32x2){0.f, 0.f};
            int deg = st[r + 1] - st[r];
            int c0 = min(64, deg);
            PROC_CHUNK(idx2[r], c0)
            for (int base = st[r] + 64; base < st[r + 1]; base += 64) {
                int cnt2 = min(64, st[r + 1] - base);
                unsigned idx = (base + lane < st[r + 1]) ? (unsigned)csr[base + lane] : 0u;
                PROC_CHUNK(idx, cnt2)
            }
            REDUCE8P()
            if (eg == 0) {
                int ln = wv * 2 + r;   // 0..15
                unsigned u0 = (unsigned)f2bf(A01.x) | ((unsigned)f2bf(A01.y) << 16);
                unsigned u1 = (unsigned)f2bf(A23.x) | ((unsigned)f2bf(A23.y) << 16);
                unsigned u2 = (unsigned)f2bf(A45.x) | ((unsigned)f2bf(A45.y) << 16);
                unsigned u3 = (unsigned)f2bf(A67.x) | ((unsigned)f2bf(A67.y) << 16);
                size_t dst = (size_t)(fb >> 2) * 512 + (size_t)((fb & 3) * 16 + ln) * 8;
                *(uint4*)(sagg + dst) = make_uint4(u0, u1, u2, u3);
            }
        }
    }
    __syncthreads();

    // ---- GEMM phase: wave wv owns j-tile js = wv (16 cols) ----
    int quad = lane >> 4;
    int mr = lane & 15;
    int js = wv;

    f32x4 acc = (f32x4){0.f, 0.f, 0.f, 0.f};

    const unsigned short* wp = Whi + (size_t)js * 4096 + (size_t)lane * 8;
    const unsigned short* sa = sagg + (size_t)lane * 8;
    const unsigned short* ha = hf + (size_t)blockIdx.x * 2048 + (size_t)lane * 8;

    uint4 pb[2][2];
#define LAYER_LOAD(s, b)                                                  \
    do {                                                                  \
        pb[b][0] = *(const uint4*)(wp + (size_t)(s) * 512);               \
        pb[b][1] = ((s) < 4)                                              \
            ? *(const uint4*)(sa + (size_t)(s) * 512)                     \
            : *(const uint4*)(ha + (size_t)((s) - 4) * 512);              \
    } while (0)

    LAYER_LOAD(0, 0);
    LAYER_LOAD(1, 1);
#pragma unroll
    for (int s = 0; s < 8; ++s) {
        int b = s & 1;
        bf16x8 bh = __builtin_bit_cast(bf16x8, pb[b][0]);
        bf16x8 A0 = __builtin_bit_cast(bf16x8, pb[b][1]);
        acc = __builtin_amdgcn_mfma_f32_16x16x32_bf16(A0, bh, acc, 0, 0, 0);
        if (s + 2 < 8) LAYER_LOAD(s + 2, b);
    }
#undef LAYER_LOAD

    // ---- epilogue: bias/relu, LDS-stage, coalesced dump ----
    int col = js * 16 + mr;
    float bias = bl[col];
    float vv[4];
#pragma unroll
    for (int r = 0; r < 4; ++r) {
        int node = node0 + quad * 4 + r;
        float v = fmaxf(acc[r] + bias, 0.f);
        vv[r] = (node < n) ? v : 0.f;
    }
    __syncthreads();   // all waves done reading sagg frags
    if (mode == 0) {
        int so = col >> 5, q2 = (col >> 3) & 3, e2 = col & 7;
#pragma unroll
        for (int r = 0; r < 4; ++r) {
            int nl = quad * 4 + r;
            sagg[so * 512 + (q2 * 16 + nl) * 8 + e2] = f2bf(vv[r]);
            s8[nl * 128 + col] = f2fp8(vv[r]);
        }
        __syncthreads();
        *(uint2*)(outf + (size_t)blockIdx.x * 2048 + (size_t)t * 4) =
            *(const uint2*)(sagg + (size_t)t * 4);
        int nl = t >> 5;
        if (node0 + nl < n)
            *(unsigned*)(out8 + (size_t)(node0 + nl) * 128 + (t & 31) * 4) =
                *(const unsigned*)(s8 + nl * 128 + (t & 31) * 4);
    } else {
        // tiled h2T: tile layout [node/16][col][16]
#pragma unroll
        for (int r = 0; r < 4; ++r)
            sagg[col * 16 + quad * 4 + r] = f2bf(vv[r]);
        __syncthreads();
        *(uint2*)(h2tb + (size_t)blockIdx.x * 2048 + (size_t)t * 4) =
            *(const uint2*)(sagg + (size_t)t * 4);
    }
}

// ------- gsum GEMM: [128 x nsp] cntb x h2tb(tiled)^T -> per-block partials -
__global__ __launch_bounds__(256) void k_gsum(
    const unsigned short* __restrict__ cntb, const unsigned short* __restrict__ h2tb,
    float* __restrict__ part, int nsp, int ksteps, int gb)
{
    int t = threadIdx.x;
    int wv = t >> 6, lane = t & 63;
    int fast = lane & 15;
    int kc = (lane >> 4) * 8;
    int kpb = (ksteps + gb - 1) / gb;
    int k0 = blockIdx.x * kpb, k1 = min(k0 + kpb, ksteps);

    f32x4 accE[8], accP[8];
#pragma unroll
    for (int i = 0; i < 8; ++i) {
        accE[i] = (f32x4){0.f, 0.f, 0.f, 0.f};
        accP[i] = (f32x4){0.f, 0.f, 0.f, 0.f};
    }

    const unsigned short* apE = cntb + (size_t)(wv * 16 + fast) * nsp + kc;
    const unsigned short* apP = apE + (size_t)64 * nsp;

    if (k0 < k1) {
        int kk = k0 * 32 + kc;
        const unsigned short* bt = h2tb + ((size_t)(kk >> 4)) * 2048 + (kk & 15);
        uint4 ca0 = *(const uint4*)(apE + k0 * 32);
        uint4 ca1 = *(const uint4*)(apP + k0 * 32);
        uint4 cb[8];
#pragma unroll
        for (int ft = 0; ft < 8; ++ft)
            cb[ft] = *(const uint4*)(bt + (size_t)(fast + ft * 16) * 16);
        for (int ks = k0; ks < k1; ++ks) {
            int ksn = min(ks + 1, k1 - 1);
            int kkn = ksn * 32 + kc;
            const unsigned short* btn = h2tb + ((size_t)(kkn >> 4)) * 2048 + (kkn & 15);
            uint4 na0 = *(const uint4*)(apE + ksn * 32);
            uint4 na1 = *(const uint4*)(apP + ksn * 32);
            uint4 nb[8];
#pragma unroll
            for (int ft = 0; ft < 8; ++ft)
                nb[ft] = *(const uint4*)(btn + (size_t)(fast + ft * 16) * 16);
            bf16x8 aE = __builtin_bit_cast(bf16x8, ca0);
            bf16x8 aP = __builtin_bit_cast(bf16x8, ca1);
#pragma unroll
            for (int ft = 0; ft < 8; ++ft) {
                bf16x8 bf = __builtin_bit_cast(bf16x8, cb[ft]);
                accE[ft] = __builtin_amdgcn_mfma_f32_16x16x32_bf16(aE, bf, accE[ft], 0, 0, 0);
                accP[ft] = __builtin_amdgcn_mfma_f32_16x16x32_bf16(aP, bf, accP[ft], 0, 0, 0);
            }
            ca0 = na0; ca1 = na1;
#pragma unroll
            for (int ft = 0; ft < 8; ++ft) cb[ft] = nb[ft];
        }
    }
    float* po = part + (size_t)blockIdx.x * 16384;
    int quad = lane >> 4, mr = lane & 15;
#pragma unroll
    for (int ft = 0; ft < 8; ++ft) {
        int col = ft * 16 + mr;
#pragma unroll
        for (int r = 0; r < 4; ++r) {
            po[(size_t)(wv * 16 + quad * 4 + r) * 128 + col] = accE[ft][r];
            po[(size_t)(64 + wv * 16 + quad * 4 + r) * 128 + col] = accP[ft][r];
        }
    }
}

// ------- final: partial reduce (8 unrolled chains) + layer 3 + head --------
__global__ __launch_bounds__(128) void k_finalred(
    const float* __restrict__ part, const int* __restrict__ batch,
    const float* __restrict__ W3l, const float* __restrict__ b3,
    const float* __restrict__ W3r,
    const float* __restrict__ Wlin, const float* __restrict__ blin,
    float* __restrict__ out, int n, int gb)
{
    __shared__ float sE[128], sP[128], tmp[128];
    int g = blockIdx.x;   // 64
    int t = threadIdx.x;  // 128
    float e0 = 0.f, e1 = 0.f, e2 = 0.f, e3 = 0.f;
    float p0 = 0.f, p1 = 0.f, p2 = 0.f, p3 = 0.f;
    int p = 0;
    for (; p + 4 <= gb; p += 4) {
        const float* q0 = part + (size_t)p * 16384;
        const float* q1 = part + (size_t)(p + 1) * 16384;
        const float* q2 = part + (size_t)(p + 2) * 16384;
        const float* q3 = part + (size_t)(p + 3) * 16384;
        e0 += q0[g * 128 + t];        e1 += q1[g * 128 + t];
        e2 += q2[g * 128 + t];        e3 += q3[g * 128 + t];
        p0 += q0[(64 + g) * 128 + t]; p1 += q1[(64 + g) * 128 + t];
        p2 += q2[(64 + g) * 128 + t]; p3 += q3[(64 + g) * 128 + t];
    }
    for (; p < gb; ++p) {
        e0 += part[(size_t)p * 16384 + g * 128 + t];
        p0 += part[(size_t)p * 16384 + (64 + g) * 128 + t];
    }
    sE[t] = (e0 + e1) + (e2 + e3);
    sP[t] = (p0 + p1) + (p2 + p3);

    int lo = 0, hi = n;
    while (lo < hi) { int m = (lo + hi) >> 1; if (batch[m] < g) lo = m + 1; else hi = m; }
    int lb = lo;
    hi = n;
    while (lo < hi) { int m = (lo + hi) >> 1; if (batch[m] < g + 1) lo = m + 1; else hi = m; }
    int cnt = lo - lb;
    float inv = (cnt > 0) ? 1.f / (float)cnt : 0.f;
    __syncthreads();

    float acc = 0.f;
    for (int k = 0; k < 128; ++k)
        acc += sE[k] * W3l[t * 128 + k] + sP[k] * W3r[t * 128 + k];
    tmp[t] = acc * inv + ((cnt > 0) ? b3[t] : 0.f);
    __syncthreads();

    if (t < 64) {
        float o = 0.f;
        for (int k = 0; k < 128; ++k)
            o += tmp[k] * Wlin[t * 128 + k];
        out[g * 64 + t] = o + blin[t];
    }
}

extern "C" void kernel_launch(void* const* d_in, const int* in_sizes, int n_in,
                              void* d_out, int out_size, void* d_ws, size_t ws_size,
                              hipStream_t stream) {
    const float* x     = (const float*)d_in[0];
    const int*   ei    = (const int*)d_in[1];
    const int*   batch = (const int*)d_in[2];
    const float* W1l = (const float*)d_in[3];
    const float* b1l = (const float*)d_in[4];
    const float* W1r = (const float*)d_in[5];
    const float* W2l = (const float*)d_in[6];
    const float* b2l = (const float*)d_in[7];
    const float* W2r = (const float*)d_in[8];
    const float* W3l = (const float*)d_in[9];
    const float* b3l = (const float*)d_in[10];
    const float* W3r = (const float*)d_in[11];
    const float* Wlin = (const float*)d_in[12];
    const float* blin = (const float*)d_in[13];

    const int N = in_sizes[2];       // 50000
    const int E = in_sizes[1] / 2;   // 800000
    const int nb = (N + 127) >> 7;   // 391 buckets
    const int epb = (E + NSB - 1) / NSB;         // 5000
    const int NSP = ((N + 31) / 32) * 32;        // 50016 (mult of 32)
    const int KSTEPS = NSP / 32;                 // 1563
    const int NCH = (NSP + CH - 1) / CH;         // 13
    const int GB = 64;                           // gsum K-split blocks

    size_t off = 0;
    auto alloc = [&](size_t bytes) {
        void* p = (char*)d_ws + off;
        off += (bytes + 255) & ~(size_t)255;
        return p;
    };
    unsigned* gbcnt = (unsigned*)alloc((size_t)NBMAX * 4);
    int* starts     = (int*)alloc((size_t)(N + 128) * 4);
    int* gestart    = (int*)alloc(256 + 64);
    unsigned short* csr_src = (unsigned short*)alloc((size_t)E * 2);
    unsigned*       binned  = (unsigned*)alloc((size_t)nb * SSTRIDE * 4);
    unsigned short* x_bf = (unsigned short*)alloc((size_t)N * 128 * 2 + 65536);
    unsigned short* hA   = (unsigned short*)alloc((size_t)N * 128 * 2 + 65536);
    unsigned char*  x8   = (unsigned char*)alloc((size_t)N * 128);
    unsigned char*  h1_8 = (unsigned char*)alloc((size_t)N * 128);
    unsigned short* h2Tb = (unsigned short*)alloc((size_t)128 * NSP * 2);
    unsigned short* cntb = (unsigned short*)alloc((size_t)128 * NSP * 2);
    unsigned short* Whi  = (unsigned short*)alloc(2 * 128 * 256 * 2);
    float*          part = (float*)alloc((size_t)GB * 16384 * 4);
    (void)ws_size;

    hipMemsetAsync(gbcnt, 0, (size_t)NBMAX * 4, stream);

    int n8 = N * 128 / 8;
    int nxblk = (n8 + 255) / 256;    // 3125

    // 1: scatter + cast + weight pack (fence-free, fixed-stride)
    k_scatcast<<<NSB + nxblk + 256, 256, 0, stream>>>(
        ei, binned, gbcnt, E, nb, epb,
        x, x_bf, x8, n8, nxblk, W1l, W1r, W2l, W2r, Whi);
    // 2: per-bucket fine sort -> DENSE csr + starts + gestart
    k_fillfine<<<nb, 256, 0, stream>>>(binned, gbcnt, batch, starts,
                                       csr_src, gestart, E, nb, N);

    int lay_grid  = (N + 15) / 16;    // 3125
    int lay2_grid = NSP / 16;         // 3126 (pad block zero-fills h2Tb tail)
    int hist_grid = 128 * NCH;        // 1664

    // 3: layer 1 (+ hist/indicator fold)
    k_layer<<<lay_grid + hist_grid, 512, 0, stream>>>(
        x8, starts, csr_src, x_bf, Whi, b1l, hA, h1_8, h2Tb,
        gestart, batch, cntb, N, NSP, 0, lay_grid, NCH);
    // 4: layer 2 -> tiled bf16 h2T
    k_layer<<<lay2_grid, 512, 0, stream>>>(
        h1_8, starts, csr_src, hA, Whi + 32768, b2l, hA, h1_8, h2Tb,
        gestart, batch, cntb, N, NSP, 1, lay2_grid, 1);
    // 5: gsumE+gsumP as one 128x128xNSP MFMA GEMM -> per-block partials
    k_gsum<<<GB, 256, 0, stream>>>(cntb, h2Tb, part, NSP, KSTEPS, GB);
    // 6: reduce partials + collapsed layer 3 + head
    k_finalred<<<64, 128, 0, stream>>>(part, batch, W3l, b3l, W3r,
                                       Wlin, blin, (float*)d_out, N, GB);
}